// Round 3
// baseline (308.137 us; speedup 1.0000x reference)
//
#include <hip/hip_runtime.h>
#include <hip/hip_bf16.h>
#include <math.h>

// MultiSimilarityLoss B=8192 D=128: sim = F·F^T via bf16 MFMA (16x16x32).
// ms1 (row min_pos/max_neg) + ms2 (masked exp sums). Fragments load directly
// from global (2 MB bf16 feats stays L1/L2-resident); no LDS in hot loops.
// R3: JSPLIT=32 -> 1024 blocks -> 4 waves/SIMD (was grid-limited at 2).

#define B_N    8192
#define DDIM   128
#define JSPLIT 32
#define JRANGE (B_N / JSPLIT)   // 256 cols per block
#define JTILES (JRANGE / 32)    // 8 j-tiles of 32 cols

typedef __attribute__((ext_vector_type(8))) short bf16x8;  // 8 bf16 = 4 VGPRs
typedef __attribute__((ext_vector_type(4))) float f32x4;

static constexpr float ONE_EPS  = 1.0f - 1e-5f;
static constexpr float F_MARGIN = 0.1f;
// exp args: pos: -2*(s-0.5) = -2s + 1 ; neg: 40*(s-0.5) = 40s - 20
static constexpr float KPA = -2.0f, KPB =  1.0f;
static constexpr float KNA = 40.0f, KNB = -20.0f;

// ---------------------------------------------------------------- cast fp32 -> bf16 (RNE)
__global__ __launch_bounds__(256)
void ms_cast(const float* __restrict__ f, ushort* __restrict__ fb)
{
    int i = (blockIdx.x * 256 + threadIdx.x) * 4;
    float4 v = *(const float4*)(f + i);
    ushort4 o;
    uint u;
    u = __float_as_uint(v.x); o.x = (ushort)((u + 0x7fffu + ((u >> 16) & 1u)) >> 16);
    u = __float_as_uint(v.y); o.y = (ushort)((u + 0x7fffu + ((u >> 16) & 1u)) >> 16);
    u = __float_as_uint(v.z); o.z = (ushort)((u + 0x7fffu + ((u >> 16) & 1u)) >> 16);
    u = __float_as_uint(v.w); o.w = (ushort)((u + 0x7fffu + ((u >> 16) & 1u)) >> 16);
    *(ushort4*)(fb + i) = o;
}

// ---------------------------------------------------------------- stage 1: min_pos / max_neg
__global__ __launch_bounds__(256, 4)
void ms1(const ushort* __restrict__ fb, const int* __restrict__ labels,
         float* __restrict__ minp_part, float* __restrict__ maxn_part)
{
    const int tid  = threadIdx.x;
    const int w    = tid >> 6;          // wave 0..3 -> 64-row strip
    const int lane = tid & 63;
    const int q    = lane >> 4;         // quad 0..3
    const int c    = lane & 15;         // col within 16-tile
    const int i0   = blockIdx.x * 256;
    const int j0   = blockIdx.y * JRANGE;
    const int arow = i0 + w * 64;

    // A fragments: wave's 64 rows, full K=128, resident in VGPRs.
    bf16x8 afr[4][4];                   // [row-tile][k-step]
    int    la[4][4];                    // row labels per (row-tile, reg)
    #pragma unroll
    for (int rt = 0; rt < 4; ++rt) {
        #pragma unroll
        for (int ks = 0; ks < 4; ++ks)
            afr[rt][ks] = *(const bf16x8*)(fb + (size_t)(arow + rt * 16 + c) * DDIM + ks * 32 + q * 8);
        #pragma unroll
        for (int r = 0; r < 4; ++r)
            la[rt][r] = labels[arow + rt * 16 + q * 4 + r];
    }

    float vmin[4][4], vmax[4][4];
    #pragma unroll
    for (int rt = 0; rt < 4; ++rt)
        #pragma unroll
        for (int r = 0; r < 4; ++r) { vmin[rt][r] = INFINITY; vmax[rt][r] = -INFINITY; }

    for (int jt = 0; jt < JTILES; ++jt) {
        const int jb = j0 + jt * 32;
        bf16x8 bfr[2][4];               // identical across block's 4 waves (L1 reuse)
        #pragma unroll
        for (int ct = 0; ct < 2; ++ct)
            #pragma unroll
            for (int ks = 0; ks < 4; ++ks)
                bfr[ct][ks] = *(const bf16x8*)(fb + (size_t)(jb + ct * 16 + c) * DDIM + ks * 32 + q * 8);
        int lbv[2] = { labels[jb + c], labels[jb + 16 + c] };

        #pragma unroll
        for (int rt = 0; rt < 4; ++rt) {
            #pragma unroll
            for (int ct = 0; ct < 2; ++ct) {
                f32x4 acc = {0.f, 0.f, 0.f, 0.f};
                #pragma unroll
                for (int ks = 0; ks < 4; ++ks)
                    acc = __builtin_amdgcn_mfma_f32_16x16x32_bf16(afr[rt][ks], bfr[ct][ks], acc, 0, 0, 0);
                int lb = lbv[ct];
                #pragma unroll
                for (int r = 0; r < 4; ++r) {
                    float s = acc[r];
                    bool same = (la[rt][r] == lb);
                    vmin[rt][r] = fminf(vmin[rt][r], (same && s < ONE_EPS) ? s : INFINITY);
                    vmax[rt][r] = fmaxf(vmax[rt][r], same ? -INFINITY : s);
                }
            }
        }
    }

    #pragma unroll
    for (int off = 1; off < 16; off <<= 1) {
        #pragma unroll
        for (int rt = 0; rt < 4; ++rt)
            #pragma unroll
            for (int r = 0; r < 4; ++r) {
                vmin[rt][r] = fminf(vmin[rt][r], __shfl_xor(vmin[rt][r], off, 64));
                vmax[rt][r] = fmaxf(vmax[rt][r], __shfl_xor(vmax[rt][r], off, 64));
            }
    }
    if (c == 0) {
        #pragma unroll
        for (int rt = 0; rt < 4; ++rt)
            #pragma unroll
            for (int r = 0; r < 4; ++r) {
                int row = arow + rt * 16 + q * 4 + r;
                minp_part[(size_t)blockIdx.y * B_N + row] = vmin[rt][r];
                maxn_part[(size_t)blockIdx.y * B_N + row] = vmax[rt][r];
            }
    }
}

// ---------------------------------------------------------------- stage 2: masked exp sums
__global__ __launch_bounds__(256, 4)
void ms2(const ushort* __restrict__ fb, const int* __restrict__ labels,
         const float* __restrict__ minp_part, const float* __restrict__ maxn_part,
         float* __restrict__ psum_part, float* __restrict__ nsum_part)
{
    const int tid  = threadIdx.x;
    const int w    = tid >> 6;
    const int lane = tid & 63;
    const int q    = lane >> 4;
    const int c    = lane & 15;
    const int i0   = blockIdx.x * 256;
    const int j0   = blockIdx.y * JRANGE;
    const int arow = i0 + w * 64;

    // inline fold of stage-1 partials; precompute per-row bounds:
    //   pb = min(1-eps, max_neg + margin)  (pos kept iff s < pb)
    //   nb = min_pos - margin              (neg kept iff s > nb)
    __shared__ float spb[256], snb[256];
    {
        int row = i0 + tid;
        float mn = INFINITY, mx = -INFINITY;
        #pragma unroll
        for (int s = 0; s < JSPLIT; ++s) {
            mn = fminf(mn, minp_part[(size_t)s * B_N + row]);
            mx = fmaxf(mx, maxn_part[(size_t)s * B_N + row]);
        }
        spb[tid] = fminf(ONE_EPS, mx + F_MARGIN);
        snb[tid] = mn - F_MARGIN;
    }
    __syncthreads();

    bf16x8 afr[4][4];
    int    la[4][4];
    float  rpb[4][4], rnb[4][4];
    #pragma unroll
    for (int rt = 0; rt < 4; ++rt) {
        #pragma unroll
        for (int ks = 0; ks < 4; ++ks)
            afr[rt][ks] = *(const bf16x8*)(fb + (size_t)(arow + rt * 16 + c) * DDIM + ks * 32 + q * 8);
        #pragma unroll
        for (int r = 0; r < 4; ++r) {
            int lrow = w * 64 + rt * 16 + q * 4 + r;
            la[rt][r]  = labels[i0 + lrow];
            rpb[rt][r] = spb[lrow];
            rnb[rt][r] = snb[lrow];
        }
    }

    float ps[4][4], ns[4][4];
    #pragma unroll
    for (int rt = 0; rt < 4; ++rt)
        #pragma unroll
        for (int r = 0; r < 4; ++r) { ps[rt][r] = 0.f; ns[rt][r] = 0.f; }

    for (int jt = 0; jt < JTILES; ++jt) {
        const int jb = j0 + jt * 32;
        bf16x8 bfr[2][4];
        #pragma unroll
        for (int ct = 0; ct < 2; ++ct)
            #pragma unroll
            for (int ks = 0; ks < 4; ++ks)
                bfr[ct][ks] = *(const bf16x8*)(fb + (size_t)(jb + ct * 16 + c) * DDIM + ks * 32 + q * 8);
        int lbv[2] = { labels[jb + c], labels[jb + 16 + c] };

        #pragma unroll
        for (int rt = 0; rt < 4; ++rt) {
            #pragma unroll
            for (int ct = 0; ct < 2; ++ct) {
                f32x4 acc = {0.f, 0.f, 0.f, 0.f};
                #pragma unroll
                for (int ks = 0; ks < 4; ++ks)
                    acc = __builtin_amdgcn_mfma_f32_16x16x32_bf16(afr[rt][ks], bfr[ct][ks], acc, 0, 0, 0);
                int lb = lbv[ct];
                #pragma unroll
                for (int r = 0; r < 4; ++r) {
                    float s = acc[r];
                    bool same = (la[rt][r] == lb);
                    float e = __expf(fmaf(s, same ? KPA : KNA, same ? KPB : KNB));
                    bool lt = s < (same ? rpb[rt][r] : rnb[rt][r]);
                    ps[rt][r] += (same && lt)   ? e : 0.0f;   // pos: s < pb
                    ns[rt][r] += (!same && !lt) ? e : 0.0f;   // neg: s >= nb (~ s > nb)
                }
            }
        }
    }

    #pragma unroll
    for (int off = 1; off < 16; off <<= 1) {
        #pragma unroll
        for (int rt = 0; rt < 4; ++rt)
            #pragma unroll
            for (int r = 0; r < 4; ++r) {
                ps[rt][r] += __shfl_xor(ps[rt][r], off, 64);
                ns[rt][r] += __shfl_xor(ns[rt][r], off, 64);
            }
    }
    if (c == 0) {
        #pragma unroll
        for (int rt = 0; rt < 4; ++rt)
            #pragma unroll
            for (int r = 0; r < 4; ++r) {
                int row = arow + rt * 16 + q * 4 + r;
                psum_part[(size_t)blockIdx.y * B_N + row] = ps[rt][r];
                nsum_part[(size_t)blockIdx.y * B_N + row] = ns[rt][r];
            }
    }
}

// ---------------------------------------------------------------- finalize
__global__ __launch_bounds__(256)
void ms_fin(const float* __restrict__ psum_part, const float* __restrict__ nsum_part,
            const float* __restrict__ minp_part, const float* __restrict__ maxn_part,
            float* __restrict__ out)
{
    int i = blockIdx.x * 256 + threadIdx.x;
    float ps = 0.f, ns = 0.f, mn = INFINITY, mx = -INFINITY;
    #pragma unroll
    for (int s = 0; s < JSPLIT; ++s) {
        ps += psum_part[(size_t)s * B_N + i];
        ns += nsum_part[(size_t)s * B_N + i];
        mn = fminf(mn, minp_part[(size_t)s * B_N + i]);
        mx = fmaxf(mx, maxn_part[(size_t)s * B_N + i]);
    }
    float rl = 0.f;
    if (mn < INFINITY && mx > -INFINITY && ps > 0.f && ns > 0.f)
        rl = log1pf(ps) * 0.5f + log1pf(ns) * 0.025f;   // /SCALE_POS, /SCALE_NEG

    #pragma unroll
    for (int off = 32; off > 0; off >>= 1) rl += __shfl_down(rl, off, 64);
    __shared__ float wsum[4];
    int lane = threadIdx.x & 63, wv = threadIdx.x >> 6;
    if (lane == 0) wsum[wv] = rl;
    __syncthreads();
    if (threadIdx.x == 0)
        atomicAdd(out, (wsum[0] + wsum[1] + wsum[2] + wsum[3]) * (1.0f / (float)B_N));
}

// ---------------------------------------------------------------- launch
extern "C" void kernel_launch(void* const* d_in, const int* in_sizes, int n_in,
                              void* d_out, int out_size, void* d_ws, size_t ws_size,
                              hipStream_t stream)
{
    const float* feats  = (const float*)d_in[0];
    const int*   labels = (const int*)d_in[1];

    char*   wsb       = (char*)d_ws;
    ushort* fb        = (ushort*)wsb;                          // 8192*128 bf16 = 2 MB
    float*  minp_part = (float*)(wsb + (size_t)2 * 1024 * 1024);
    float*  maxn_part = minp_part + (size_t)JSPLIT * B_N;      // 1 MB each
    float*  psum_part = maxn_part + (size_t)JSPLIT * B_N;
    float*  nsum_part = psum_part + (size_t)JSPLIT * B_N;

    hipMemsetAsync(d_out, 0, sizeof(float), stream);

    ms_cast<<<(B_N * DDIM) / (256 * 4), 256, 0, stream>>>(feats, fb);
    ms1<<<dim3(B_N / 256, JSPLIT), 256, 0, stream>>>(fb, labels, minp_part, maxn_part);
    ms2<<<dim3(B_N / 256, JSPLIT), 256, 0, stream>>>(fb, labels, minp_part, maxn_part,
                                                     psum_part, nsum_part);
    ms_fin<<<B_N / 256, 256, 0, stream>>>(psum_part, nsum_part,
                                          minp_part, maxn_part, (float*)d_out);
}

// Round 4
// 175.735 us; speedup vs baseline: 1.7534x; 1.7534x over previous
//
#include <hip/hip_runtime.h>
#include <hip/hip_bf16.h>
#include <math.h>

// MultiSimilarityLoss B=8192 D=128: sim = F·F^T via bf16 MFMA (16x16x32).
// ms1 (row min_pos/max_neg) + ms2 (masked exp sums). Fragments load directly
// from global (2 MB bf16 feats stays L1/L2-resident); no LDS in hot loops.
// R4: JSPLIT=32 (1024 blocks = 4/CU) but NO min-waves launch-bounds clamp —
// R3's (256,4) forced VGPR=64 and spilled (FETCH 9MB->320MB, 2x regression).
// 116 VGPRs already allows 4 waves/SIMD (steps at 64/128/256).

#define B_N    8192
#define DDIM   128
#define JSPLIT 32
#define JRANGE (B_N / JSPLIT)   // 256 cols per block
#define JTILES (JRANGE / 32)    // 8 j-tiles of 32 cols

typedef __attribute__((ext_vector_type(8))) short bf16x8;  // 8 bf16 = 4 VGPRs
typedef __attribute__((ext_vector_type(4))) float f32x4;

static constexpr float ONE_EPS  = 1.0f - 1e-5f;
static constexpr float F_MARGIN = 0.1f;
// exp args: pos: -2*(s-0.5) = -2s + 1 ; neg: 40*(s-0.5) = 40s - 20
static constexpr float KPA = -2.0f, KPB =  1.0f;
static constexpr float KNA = 40.0f, KNB = -20.0f;

// ---------------------------------------------------------------- cast fp32 -> bf16 (RNE)
__global__ __launch_bounds__(256)
void ms_cast(const float* __restrict__ f, ushort* __restrict__ fb)
{
    int i = (blockIdx.x * 256 + threadIdx.x) * 4;
    float4 v = *(const float4*)(f + i);
    ushort4 o;
    uint u;
    u = __float_as_uint(v.x); o.x = (ushort)((u + 0x7fffu + ((u >> 16) & 1u)) >> 16);
    u = __float_as_uint(v.y); o.y = (ushort)((u + 0x7fffu + ((u >> 16) & 1u)) >> 16);
    u = __float_as_uint(v.z); o.z = (ushort)((u + 0x7fffu + ((u >> 16) & 1u)) >> 16);
    u = __float_as_uint(v.w); o.w = (ushort)((u + 0x7fffu + ((u >> 16) & 1u)) >> 16);
    *(ushort4*)(fb + i) = o;
}

// ---------------------------------------------------------------- stage 1: min_pos / max_neg
__global__ __launch_bounds__(256)
void ms1(const ushort* __restrict__ fb, const int* __restrict__ labels,
         float* __restrict__ minp_part, float* __restrict__ maxn_part)
{
    const int tid  = threadIdx.x;
    const int w    = tid >> 6;          // wave 0..3 -> 64-row strip
    const int lane = tid & 63;
    const int q    = lane >> 4;         // quad 0..3
    const int c    = lane & 15;         // col within 16-tile
    const int i0   = blockIdx.x * 256;
    const int j0   = blockIdx.y * JRANGE;
    const int arow = i0 + w * 64;

    // A fragments: wave's 64 rows, full K=128, resident in VGPRs.
    bf16x8 afr[4][4];                   // [row-tile][k-step]
    int    la[4][4];                    // row labels per (row-tile, reg)
    #pragma unroll
    for (int rt = 0; rt < 4; ++rt) {
        #pragma unroll
        for (int ks = 0; ks < 4; ++ks)
            afr[rt][ks] = *(const bf16x8*)(fb + (size_t)(arow + rt * 16 + c) * DDIM + ks * 32 + q * 8);
        #pragma unroll
        for (int r = 0; r < 4; ++r)
            la[rt][r] = labels[arow + rt * 16 + q * 4 + r];
    }

    float vmin[4][4], vmax[4][4];
    #pragma unroll
    for (int rt = 0; rt < 4; ++rt)
        #pragma unroll
        for (int r = 0; r < 4; ++r) { vmin[rt][r] = INFINITY; vmax[rt][r] = -INFINITY; }

    for (int jt = 0; jt < JTILES; ++jt) {
        const int jb = j0 + jt * 32;
        bf16x8 bfr[2][4];               // identical across block's 4 waves (L1 reuse)
        #pragma unroll
        for (int ct = 0; ct < 2; ++ct)
            #pragma unroll
            for (int ks = 0; ks < 4; ++ks)
                bfr[ct][ks] = *(const bf16x8*)(fb + (size_t)(jb + ct * 16 + c) * DDIM + ks * 32 + q * 8);
        int lbv[2] = { labels[jb + c], labels[jb + 16 + c] };

        #pragma unroll
        for (int rt = 0; rt < 4; ++rt) {
            #pragma unroll
            for (int ct = 0; ct < 2; ++ct) {
                f32x4 acc = {0.f, 0.f, 0.f, 0.f};
                #pragma unroll
                for (int ks = 0; ks < 4; ++ks)
                    acc = __builtin_amdgcn_mfma_f32_16x16x32_bf16(afr[rt][ks], bfr[ct][ks], acc, 0, 0, 0);
                int lb = lbv[ct];
                #pragma unroll
                for (int r = 0; r < 4; ++r) {
                    float s = acc[r];
                    bool same = (la[rt][r] == lb);
                    vmin[rt][r] = fminf(vmin[rt][r], (same && s < ONE_EPS) ? s : INFINITY);
                    vmax[rt][r] = fmaxf(vmax[rt][r], same ? -INFINITY : s);
                }
            }
        }
    }

    #pragma unroll
    for (int off = 1; off < 16; off <<= 1) {
        #pragma unroll
        for (int rt = 0; rt < 4; ++rt)
            #pragma unroll
            for (int r = 0; r < 4; ++r) {
                vmin[rt][r] = fminf(vmin[rt][r], __shfl_xor(vmin[rt][r], off, 64));
                vmax[rt][r] = fmaxf(vmax[rt][r], __shfl_xor(vmax[rt][r], off, 64));
            }
    }
    if (c == 0) {
        #pragma unroll
        for (int rt = 0; rt < 4; ++rt)
            #pragma unroll
            for (int r = 0; r < 4; ++r) {
                int row = arow + rt * 16 + q * 4 + r;
                minp_part[(size_t)blockIdx.y * B_N + row] = vmin[rt][r];
                maxn_part[(size_t)blockIdx.y * B_N + row] = vmax[rt][r];
            }
    }
}

// ---------------------------------------------------------------- stage 2: masked exp sums
__global__ __launch_bounds__(256)
void ms2(const ushort* __restrict__ fb, const int* __restrict__ labels,
         const float* __restrict__ minp_part, const float* __restrict__ maxn_part,
         float* __restrict__ psum_part, float* __restrict__ nsum_part)
{
    const int tid  = threadIdx.x;
    const int w    = tid >> 6;
    const int lane = tid & 63;
    const int q    = lane >> 4;
    const int c    = lane & 15;
    const int i0   = blockIdx.x * 256;
    const int j0   = blockIdx.y * JRANGE;
    const int arow = i0 + w * 64;

    // inline fold of stage-1 partials; precompute per-row bounds:
    //   pb = min(1-eps, max_neg + margin)  (pos kept iff s < pb)
    //   nb = min_pos - margin              (neg kept iff s > nb)
    __shared__ float spb[256], snb[256];
    {
        int row = i0 + tid;
        float mn = INFINITY, mx = -INFINITY;
        #pragma unroll
        for (int s = 0; s < JSPLIT; ++s) {
            mn = fminf(mn, minp_part[(size_t)s * B_N + row]);
            mx = fmaxf(mx, maxn_part[(size_t)s * B_N + row]);
        }
        spb[tid] = fminf(ONE_EPS, mx + F_MARGIN);
        snb[tid] = mn - F_MARGIN;
    }
    __syncthreads();

    bf16x8 afr[4][4];
    int    la[4][4];
    float  rpb[4][4], rnb[4][4];
    #pragma unroll
    for (int rt = 0; rt < 4; ++rt) {
        #pragma unroll
        for (int ks = 0; ks < 4; ++ks)
            afr[rt][ks] = *(const bf16x8*)(fb + (size_t)(arow + rt * 16 + c) * DDIM + ks * 32 + q * 8);
        #pragma unroll
        for (int r = 0; r < 4; ++r) {
            int lrow = w * 64 + rt * 16 + q * 4 + r;
            la[rt][r]  = labels[i0 + lrow];
            rpb[rt][r] = spb[lrow];
            rnb[rt][r] = snb[lrow];
        }
    }

    float ps[4][4], ns[4][4];
    #pragma unroll
    for (int rt = 0; rt < 4; ++rt)
        #pragma unroll
        for (int r = 0; r < 4; ++r) { ps[rt][r] = 0.f; ns[rt][r] = 0.f; }

    for (int jt = 0; jt < JTILES; ++jt) {
        const int jb = j0 + jt * 32;
        bf16x8 bfr[2][4];
        #pragma unroll
        for (int ct = 0; ct < 2; ++ct)
            #pragma unroll
            for (int ks = 0; ks < 4; ++ks)
                bfr[ct][ks] = *(const bf16x8*)(fb + (size_t)(jb + ct * 16 + c) * DDIM + ks * 32 + q * 8);
        int lbv[2] = { labels[jb + c], labels[jb + 16 + c] };

        #pragma unroll
        for (int rt = 0; rt < 4; ++rt) {
            #pragma unroll
            for (int ct = 0; ct < 2; ++ct) {
                f32x4 acc = {0.f, 0.f, 0.f, 0.f};
                #pragma unroll
                for (int ks = 0; ks < 4; ++ks)
                    acc = __builtin_amdgcn_mfma_f32_16x16x32_bf16(afr[rt][ks], bfr[ct][ks], acc, 0, 0, 0);
                int lb = lbv[ct];
                #pragma unroll
                for (int r = 0; r < 4; ++r) {
                    float s = acc[r];
                    bool same = (la[rt][r] == lb);
                    float e = __expf(fmaf(s, same ? KPA : KNA, same ? KPB : KNB));
                    bool lt = s < (same ? rpb[rt][r] : rnb[rt][r]);
                    ps[rt][r] += (same && lt)   ? e : 0.0f;   // pos: s < pb
                    ns[rt][r] += (!same && !lt) ? e : 0.0f;   // neg: s >= nb
                }
            }
        }
    }

    #pragma unroll
    for (int off = 1; off < 16; off <<= 1) {
        #pragma unroll
        for (int rt = 0; rt < 4; ++rt)
            #pragma unroll
            for (int r = 0; r < 4; ++r) {
                ps[rt][r] += __shfl_xor(ps[rt][r], off, 64);
                ns[rt][r] += __shfl_xor(ns[rt][r], off, 64);
            }
    }
    if (c == 0) {
        #pragma unroll
        for (int rt = 0; rt < 4; ++rt)
            #pragma unroll
            for (int r = 0; r < 4; ++r) {
                int row = arow + rt * 16 + q * 4 + r;
                psum_part[(size_t)blockIdx.y * B_N + row] = ps[rt][r];
                nsum_part[(size_t)blockIdx.y * B_N + row] = ns[rt][r];
            }
    }
}

// ---------------------------------------------------------------- finalize
__global__ __launch_bounds__(256)
void ms_fin(const float* __restrict__ psum_part, const float* __restrict__ nsum_part,
            const float* __restrict__ minp_part, const float* __restrict__ maxn_part,
            float* __restrict__ out)
{
    int i = blockIdx.x * 256 + threadIdx.x;
    float ps = 0.f, ns = 0.f, mn = INFINITY, mx = -INFINITY;
    #pragma unroll
    for (int s = 0; s < JSPLIT; ++s) {
        ps += psum_part[(size_t)s * B_N + i];
        ns += nsum_part[(size_t)s * B_N + i];
        mn = fminf(mn, minp_part[(size_t)s * B_N + i]);
        mx = fmaxf(mx, maxn_part[(size_t)s * B_N + i]);
    }
    float rl = 0.f;
    if (mn < INFINITY && mx > -INFINITY && ps > 0.f && ns > 0.f)
        rl = log1pf(ps) * 0.5f + log1pf(ns) * 0.025f;   // /SCALE_POS, /SCALE_NEG

    #pragma unroll
    for (int off = 32; off > 0; off >>= 1) rl += __shfl_down(rl, off, 64);
    __shared__ float wsum[4];
    int lane = threadIdx.x & 63, wv = threadIdx.x >> 6;
    if (lane == 0) wsum[wv] = rl;
    __syncthreads();
    if (threadIdx.x == 0)
        atomicAdd(out, (wsum[0] + wsum[1] + wsum[2] + wsum[3]) * (1.0f / (float)B_N));
}

// ---------------------------------------------------------------- launch
extern "C" void kernel_launch(void* const* d_in, const int* in_sizes, int n_in,
                              void* d_out, int out_size, void* d_ws, size_t ws_size,
                              hipStream_t stream)
{
    const float* feats  = (const float*)d_in[0];
    const int*   labels = (const int*)d_in[1];

    char*   wsb       = (char*)d_ws;
    ushort* fb        = (ushort*)wsb;                          // 8192*128 bf16 = 2 MB
    float*  minp_part = (float*)(wsb + (size_t)2 * 1024 * 1024);
    float*  maxn_part = minp_part + (size_t)JSPLIT * B_N;      // 1 MB each
    float*  psum_part = maxn_part + (size_t)JSPLIT * B_N;
    float*  nsum_part = psum_part + (size_t)JSPLIT * B_N;

    hipMemsetAsync(d_out, 0, sizeof(float), stream);

    ms_cast<<<(B_N * DDIM) / (256 * 4), 256, 0, stream>>>(feats, fb);
    ms1<<<dim3(B_N / 256, JSPLIT), 256, 0, stream>>>(fb, labels, minp_part, maxn_part);
    ms2<<<dim3(B_N / 256, JSPLIT), 256, 0, stream>>>(fb, labels, minp_part, maxn_part,
                                                     psum_part, nsum_part);
    ms_fin<<<B_N / 256, 256, 0, stream>>>(psum_part, nsum_part,
                                          minp_part, maxn_part, (float*)d_out);
}

// Round 5
// 159.549 us; speedup vs baseline: 1.9313x; 1.1014x over previous
//
#include <hip/hip_runtime.h>
#include <hip/hip_bf16.h>
#include <math.h>

// MultiSimilarityLoss B=8192 D=128: sim = F·F^T via bf16 MFMA (16x16x32).
// R5: transposed MFMA roles — streamed j-side is the A operand, persistent
// i-side is the B operand, so D's col (lane&15) = i and ALL per-i state
// (accumulators/bounds/labels) is 1 reg per 16-i group per lane.
// Per-wave live regs ~115 (was ~180 w/ AGPRs) -> (256,4) fits the 128-reg
// quantum -> 4 waves/SIMD (R2/R4 were pinned at 2 by the unified VGPR+AGPR
// budget; R3's (256,4) spilled because live state was ~180).

#define B_N    8192
#define DDIM   128
#define JSPLIT 32
#define JRANGE (B_N / JSPLIT)    // 256 j per block
#define JT     16                // j-tile rows per iteration
#define NJT    (JRANGE / JT)     // 16 iterations
#define NG     4                 // 16-col i-groups per wave (64 i per wave)

typedef __attribute__((ext_vector_type(8))) short bf16x8;  // 8 bf16 = 4 VGPRs
typedef __attribute__((ext_vector_type(4))) float f32x4;

static constexpr float ONE_EPS  = 1.0f - 1e-5f;
static constexpr float F_MARGIN = 0.1f;
// exp args: pos: -2*(s-0.5) = -2s+1 ; neg: 40*(s-0.5) = 40s-20
static constexpr float KPA = -2.0f, KPB =  1.0f;
static constexpr float KNA = 40.0f, KNB = -20.0f;

// ---------------------------------------------------------------- cast fp32 -> bf16 (RNE)
__global__ __launch_bounds__(256)
void ms_cast(const float* __restrict__ f, ushort* __restrict__ fb)
{
    int i = (blockIdx.x * 256 + threadIdx.x) * 4;
    float4 v = *(const float4*)(f + i);
    ushort4 o;
    uint u;
    u = __float_as_uint(v.x); o.x = (ushort)((u + 0x7fffu + ((u >> 16) & 1u)) >> 16);
    u = __float_as_uint(v.y); o.y = (ushort)((u + 0x7fffu + ((u >> 16) & 1u)) >> 16);
    u = __float_as_uint(v.z); o.z = (ushort)((u + 0x7fffu + ((u >> 16) & 1u)) >> 16);
    u = __float_as_uint(v.w); o.w = (ushort)((u + 0x7fffu + ((u >> 16) & 1u)) >> 16);
    *(ushort4*)(fb + i) = o;
}

// ---------------------------------------------------------------- stage 1: min_pos / max_neg
__global__ __launch_bounds__(256, 4)
void ms1(const ushort* __restrict__ fb, const int* __restrict__ labels,
         float* __restrict__ minp_part, float* __restrict__ maxn_part)
{
    const int tid  = threadIdx.x;
    const int w    = tid >> 6;
    const int lane = tid & 63;
    const int q    = lane >> 4;      // quad: selects k-chunk (operands) / j-rows (output)
    const int c    = lane & 15;      // i within 16-group (output col)
    const int i0   = blockIdx.x * 256;
    const int j0   = blockIdx.y * JRANGE;
    const int iw0  = i0 + w * 64;

    // persistent i-side fragments (B operand): 64 i per wave, K=128
    bf16x8 ifr[NG][4];
    int    li[NG];
    #pragma unroll
    for (int g = 0; g < NG; ++g) {
        int row = iw0 + g * 16 + c;
        #pragma unroll
        for (int ks = 0; ks < 4; ++ks)
            ifr[g][ks] = *(const bf16x8*)(fb + row * DDIM + ks * 32 + q * 8);
        li[g] = labels[row];
    }

    float vmin[NG], vmax[NG];
    #pragma unroll
    for (int g = 0; g < NG; ++g) { vmin[g] = INFINITY; vmax[g] = -INFINITY; }

    #pragma unroll 1
    for (int jt = 0; jt < NJT; ++jt) {
        const int jb = j0 + jt * JT;
        bf16x8 jfr[4];                       // streamed j-side (A operand), 16 j rows
        #pragma unroll
        for (int ks = 0; ks < 4; ++ks)
            jfr[ks] = *(const bf16x8*)(fb + (jb + c) * DDIM + ks * 32 + q * 8);
        int4 lj = *(const int4*)(labels + jb + q * 4);   // labels of this quad's 4 j rows

        #pragma unroll
        for (int g = 0; g < NG; ++g) {
            f32x4 acc = {0.f, 0.f, 0.f, 0.f};
            #pragma unroll
            for (int ks = 0; ks < 4; ++ks)
                acc = __builtin_amdgcn_mfma_f32_16x16x32_bf16(jfr[ks], ifr[g][ks], acc, 0, 0, 0);
            // D: row (j) = q*4 + r, col (i) = c
            #pragma unroll
            for (int r = 0; r < 4; ++r) {
                float s = acc[r];
                int ljr = (r == 0) ? lj.x : (r == 1) ? lj.y : (r == 2) ? lj.z : lj.w;
                bool same = (li[g] == ljr);
                vmin[g] = fminf(vmin[g], (same && s < ONE_EPS) ? s : INFINITY);
                vmax[g] = fmaxf(vmax[g], same ? -INFINITY : s);
            }
        }
    }

    // fold the 4 quads' j-partitions: lanes c, c+16, c+32, c+48 share i
    #pragma unroll
    for (int g = 0; g < NG; ++g) {
        vmin[g] = fminf(vmin[g], __shfl_xor(vmin[g], 16, 64));
        vmin[g] = fminf(vmin[g], __shfl_xor(vmin[g], 32, 64));
        vmax[g] = fmaxf(vmax[g], __shfl_xor(vmax[g], 16, 64));
        vmax[g] = fmaxf(vmax[g], __shfl_xor(vmax[g], 32, 64));
    }
    if (q == 0) {
        #pragma unroll
        for (int g = 0; g < NG; ++g) {
            int row = iw0 + g * 16 + c;
            minp_part[blockIdx.y * B_N + row] = vmin[g];
            maxn_part[blockIdx.y * B_N + row] = vmax[g];
        }
    }
}

// ---------------------------------------------------------------- stage 2: masked exp sums
__global__ __launch_bounds__(256, 4)
void ms2(const ushort* __restrict__ fb, const int* __restrict__ labels,
         const float* __restrict__ minp_part, const float* __restrict__ maxn_part,
         float* __restrict__ psum_part, float* __restrict__ nsum_part)
{
    const int tid  = threadIdx.x;
    const int w    = tid >> 6;
    const int lane = tid & 63;
    const int q    = lane >> 4;
    const int c    = lane & 15;
    const int i0   = blockIdx.x * 256;
    const int j0   = blockIdx.y * JRANGE;
    const int iw0  = i0 + w * 64;

    // fold stage-1 partials -> per-row bounds:
    //   pb = min(1-eps, max_neg + margin)  (pos kept iff s < pb)
    //   nb = min_pos - margin              (neg kept iff s >= nb)
    __shared__ float spb[256], snb[256];
    {
        int row = i0 + tid;
        float mn = INFINITY, mx = -INFINITY;
        #pragma unroll
        for (int s = 0; s < JSPLIT; ++s) {
            mn = fminf(mn, minp_part[s * B_N + row]);
            mx = fmaxf(mx, maxn_part[s * B_N + row]);
        }
        spb[tid] = fminf(ONE_EPS, mx + F_MARGIN);
        snb[tid] = mn - F_MARGIN;
    }
    __syncthreads();

    bf16x8 ifr[NG][4];
    int    li[NG];
    float  pb[NG], nb[NG];
    #pragma unroll
    for (int g = 0; g < NG; ++g) {
        int row = iw0 + g * 16 + c;
        #pragma unroll
        for (int ks = 0; ks < 4; ++ks)
            ifr[g][ks] = *(const bf16x8*)(fb + row * DDIM + ks * 32 + q * 8);
        li[g] = labels[row];
        pb[g] = spb[w * 64 + g * 16 + c];
        nb[g] = snb[w * 64 + g * 16 + c];
    }

    float ps[NG], ns[NG];
    #pragma unroll
    for (int g = 0; g < NG; ++g) { ps[g] = 0.f; ns[g] = 0.f; }

    #pragma unroll 1
    for (int jt = 0; jt < NJT; ++jt) {
        const int jb = j0 + jt * JT;
        bf16x8 jfr[4];
        #pragma unroll
        for (int ks = 0; ks < 4; ++ks)
            jfr[ks] = *(const bf16x8*)(fb + (jb + c) * DDIM + ks * 32 + q * 8);
        int4 lj = *(const int4*)(labels + jb + q * 4);

        #pragma unroll
        for (int g = 0; g < NG; ++g) {
            f32x4 acc = {0.f, 0.f, 0.f, 0.f};
            #pragma unroll
            for (int ks = 0; ks < 4; ++ks)
                acc = __builtin_amdgcn_mfma_f32_16x16x32_bf16(jfr[ks], ifr[g][ks], acc, 0, 0, 0);
            #pragma unroll
            for (int r = 0; r < 4; ++r) {
                float s = acc[r];
                int ljr = (r == 0) ? lj.x : (r == 1) ? lj.y : (r == 2) ? lj.z : lj.w;
                bool same = (li[g] == ljr);
                float e = __expf(fmaf(s, same ? KPA : KNA, same ? KPB : KNB));
                bool lt = s < (same ? pb[g] : nb[g]);
                ps[g] += (same && lt)   ? e : 0.0f;   // pos: s < pb
                ns[g] += (!same && !lt) ? e : 0.0f;   // neg: s >= nb
            }
        }
    }

    #pragma unroll
    for (int g = 0; g < NG; ++g) {
        ps[g] += __shfl_xor(ps[g], 16, 64);
        ps[g] += __shfl_xor(ps[g], 32, 64);
        ns[g] += __shfl_xor(ns[g], 16, 64);
        ns[g] += __shfl_xor(ns[g], 32, 64);
    }
    if (q == 0) {
        #pragma unroll
        for (int g = 0; g < NG; ++g) {
            int row = iw0 + g * 16 + c;
            psum_part[blockIdx.y * B_N + row] = ps[g];
            nsum_part[blockIdx.y * B_N + row] = ns[g];
        }
    }
}

// ---------------------------------------------------------------- finalize
__global__ __launch_bounds__(256)
void ms_fin(const float* __restrict__ psum_part, const float* __restrict__ nsum_part,
            const float* __restrict__ minp_part, const float* __restrict__ maxn_part,
            float* __restrict__ out)
{
    int i = blockIdx.x * 256 + threadIdx.x;
    float ps = 0.f, ns = 0.f, mn = INFINITY, mx = -INFINITY;
    #pragma unroll
    for (int s = 0; s < JSPLIT; ++s) {
        ps += psum_part[s * B_N + i];
        ns += nsum_part[s * B_N + i];
        mn = fminf(mn, minp_part[s * B_N + i]);
        mx = fmaxf(mx, maxn_part[s * B_N + i]);
    }
    float rl = 0.f;
    if (mn < INFINITY && mx > -INFINITY && ps > 0.f && ns > 0.f)
        rl = log1pf(ps) * 0.5f + log1pf(ns) * 0.025f;   // /SCALE_POS, /SCALE_NEG

    #pragma unroll
    for (int off = 32; off > 0; off >>= 1) rl += __shfl_down(rl, off, 64);
    __shared__ float wsum[4];
    int lane = threadIdx.x & 63, wv = threadIdx.x >> 6;
    if (lane == 0) wsum[wv] = rl;
    __syncthreads();
    if (threadIdx.x == 0)
        atomicAdd(out, (wsum[0] + wsum[1] + wsum[2] + wsum[3]) * (1.0f / (float)B_N));
}

// ---------------------------------------------------------------- launch
extern "C" void kernel_launch(void* const* d_in, const int* in_sizes, int n_in,
                              void* d_out, int out_size, void* d_ws, size_t ws_size,
                              hipStream_t stream)
{
    const float* feats  = (const float*)d_in[0];
    const int*   labels = (const int*)d_in[1];

    char*   wsb       = (char*)d_ws;
    ushort* fb        = (ushort*)wsb;                          // 8192*128 bf16 = 2 MB
    float*  minp_part = (float*)(wsb + (size_t)2 * 1024 * 1024);
    float*  maxn_part = minp_part + (size_t)JSPLIT * B_N;      // 1 MB each
    float*  psum_part = maxn_part + (size_t)JSPLIT * B_N;
    float*  nsum_part = psum_part + (size_t)JSPLIT * B_N;

    hipMemsetAsync(d_out, 0, sizeof(float), stream);

    ms_cast<<<(B_N * DDIM) / (256 * 4), 256, 0, stream>>>(feats, fb);
    ms1<<<dim3(B_N / 256, JSPLIT), 256, 0, stream>>>(fb, labels, minp_part, maxn_part);
    ms2<<<dim3(B_N / 256, JSPLIT), 256, 0, stream>>>(fb, labels, minp_part, maxn_part,
                                                     psum_part, nsum_part);
    ms_fin<<<B_N / 256, 256, 0, stream>>>(psum_part, nsum_part,
                                          minp_part, maxn_part, (float*)d_out);
}